// Round 1
// 521.136 us; speedup vs baseline: 1.1266x; 1.1266x over previous
//
#include <hip/hip_runtime.h>
#include <hip/hip_bf16.h>

#define B_DIM 4096
#define C_DIM 1024
#define N_DIM 256
#define M_DIM 64
#define GPAD  208   // padded gate count (13 MFMA n-tiles of 16)
#define NG    198   // real gates: 64 k | 1 beta | 1 g | 3 s | 1 gamma | 64 e | 64 a
#define EPSC  1e-8f
#define PDS   17    // partial-reduce LDS row stride (odd -> conflict-free transpose read)

typedef __attribute__((ext_vector_type(8))) short bfrag_t;  // 8 bf16 (4 VGPRs)
typedef __attribute__((ext_vector_type(4))) float ffrag_t;  // 4 fp32 acc

__device__ __forceinline__ short f2b(float f) {
    __hip_bfloat16 h = __float2bfloat16(f);
    return *reinterpret_cast<short*>(&h);
}
__device__ __forceinline__ float softplus_f(float x) {
    return fmaxf(x, 0.f) + log1pf(expf(-fabsf(x)));
}
__device__ __forceinline__ float sigmoid_f(float x) {
    return 1.f / (1.f + expf(-x));
}
__device__ __forceinline__ float warp_red_max(float v) {
#pragma unroll
    for (int off = 32; off; off >>= 1) v = fmaxf(v, __shfl_xor(v, off));
    return v;
}
__device__ __forceinline__ float warp_red_sum(float v) {
#pragma unroll
    for (int off = 32; off; off >>= 1) v += __shfl_xor(v, off);
    return v;
}

// ---------------------------------------------------------------------------
// Kernel 0a: pack 7 fp32 weight matrices -> one bf16 Wcat[GPAD][C_DIM] in ws.
// Rows 198..207 are zeroed (padding tile 12).
// ---------------------------------------------------------------------------
__global__ __launch_bounds__(256) void build_wcat(
    const float* __restrict__ Wk, const float* __restrict__ Wbeta,
    const float* __restrict__ Wg, const float* __restrict__ Ws,
    const float* __restrict__ Wgamma, const float* __restrict__ We,
    const float* __restrict__ Wa, short* __restrict__ wcat)
{
    int idx = blockIdx.x * 256 + threadIdx.x;
    if (idx >= GPAD * C_DIM) return;
    int n = idx >> 10, k = idx & (C_DIM - 1);
    float v;
    if (n < 64)        v = Wk[n * C_DIM + k];
    else if (n == 64)  v = Wbeta[k];
    else if (n == 65)  v = Wg[k];
    else if (n < 69)   v = Ws[(n - 66) * C_DIM + k];
    else if (n == 69)  v = Wgamma[k];
    else if (n < 134)  v = We[(n - 70) * C_DIM + k];
    else if (n < NG)   v = Wa[(n - 134) * C_DIM + k];
    else               v = 0.f;
    wcat[idx] = f2b(v);
}

// ---------------------------------------------------------------------------
// Kernel 0b: convert emb fp32 -> bf16 once (removes cvt chain + halves A bytes
// in the GEMM hot loop). 8 elements/thread, fully coalesced.
// ---------------------------------------------------------------------------
__global__ __launch_bounds__(256) void cvt_emb(
    const float* __restrict__ emb, short* __restrict__ embh)
{
    int idx = (blockIdx.x * 256 + threadIdx.x) << 3;
    if (idx >= B_DIM * C_DIM) return;
    float4 a0 = *(const float4*)(emb + idx);
    float4 a1 = *(const float4*)(emb + idx + 4);
    bfrag_t f;
    f[0] = f2b(a0.x); f[1] = f2b(a0.y); f[2] = f2b(a0.z); f[3] = f2b(a0.w);
    f[4] = f2b(a1.x); f[5] = f2b(a1.y); f[6] = f2b(a1.z); f[7] = f2b(a1.w);
    *(bfrag_t*)(embh + idx) = f;
}

// ---------------------------------------------------------------------------
// Kernel 1: gates GEMM  pre[b, n] = emb[b,:] . Wcat[n,:]  (raw, no bias/act)
// v2: 1024 blocks x 4 waves (4 waves/SIMD occupancy vs 1 wave/CU before).
// Each wave: 16 batch rows x ONE 16-gate tile, bf16 A read direct.
// ---------------------------------------------------------------------------
__global__ __launch_bounds__(256) void gates_gemm(
    const short* __restrict__ embh,
    const short* __restrict__ wcat,
    float* __restrict__ gates)
{
    const int wave = threadIdx.x >> 6;
    const int lane = threadIdx.x & 63;
    const int rg   = blockIdx.x >> 2;                  // 0..255 row-group
    const int tt   = ((blockIdx.x & 3) << 2) + wave;   // 0..15 tile
    if (tt >= 13) return;                              // padding waves exit

    const int m  = lane & 15;
    const int ko = (lane >> 4) << 3;                   // k sub-offset 0/8/16/24

    const short* arow = embh + (size_t)(rg * 16 + m) * C_DIM + ko;
    const short* brow = wcat + (size_t)(tt * 16 + m) * C_DIM + ko;

    ffrag_t acc = (ffrag_t)(0.f);
#pragma unroll 4
    for (int k = 0; k < C_DIM; k += 32) {
        bfrag_t af = *(const bfrag_t*)(arow + k);
        bfrag_t bf = *(const bfrag_t*)(brow + k);
        acc = __builtin_amdgcn_mfma_f32_16x16x32_bf16(af, bf, acc, 0, 0, 0);
    }

    // C/D layout (m89-verified): col(n) = lane&15, row(m) = (lane>>4)*4 + reg
    const int crow = rg * 16 + ((lane >> 4) << 2);
    const int n = (tt << 4) + m;
#pragma unroll
    for (int rr = 0; rr < 4; ++rr)
        gates[(size_t)(crow + rr) * GPAD + n] = acc[rr];
}

// ---------------------------------------------------------------------------
// Kernel 2: fused NTM write head. One block (256 threads) per batch row.
// v2: memory tile held in REGISTERS (16 x float4/thread, coalesced), no 70 KB
// LDS staging. Cross-lane dot/norm reduction via 35 KB padded LDS partials.
// LDS 70->39 KB, target 4 blocks/CU (vs 2).
// Thread t owns column-chunk c=t&15 (floats 4c..4c+3) of rows r+16i, r=t>>4.
// ---------------------------------------------------------------------------
__global__ __launch_bounds__(256, 4) void ntm_fused(
    const float* __restrict__ w_prev,    // [B,N]
    const float* __restrict__ memory,    // [B,N,M]
    const float* __restrict__ gates,     // [B,GPAD] raw pre-activations
    const float* __restrict__ bk, const float* __restrict__ bbeta,
    const float* __restrict__ bg, const float* __restrict__ bs,
    const float* __restrict__ bgamma, const float* __restrict__ be,
    const float* __restrict__ ba,
    float* __restrict__ out_w,           // [B,N]
    float* __restrict__ out_mem)         // [B,N,M]
{
    const int b = blockIdx.x;
    const int t = threadIdx.x;
    const int r = t >> 4;     // 0..15
    const int c = t & 15;     // 0..15

    __shared__ __align__(16) float pdot[N_DIM * PDS];   // 17.4 KB
    __shared__ __align__(16) float pnrm[N_DIM * PDS];   // 17.4 KB
    __shared__ __align__(16) float pre[NG];
    __shared__ __align__(16) float kvf[M_DIM];
    __shared__ __align__(16) float ev[M_DIM];
    __shared__ __align__(16) float av[M_DIM];
    __shared__ float wgs[N_DIM];
    __shared__ float wsh[N_DIM];
    __shared__ float scal[8];   // 0 beta, 1 g, 2 gamma, 3..5 s, 6 k_norm
    __shared__ float redA[4], redB[4], redC[4];

    // ---- issue memory[b] loads FIRST (coalesced float4, 64 VGPRs) ----
    const float4* msrc = (const float4*)(memory + (size_t)b * (N_DIM * M_DIM));
    float4 v[16];
#pragma unroll
    for (int i = 0; i < 16; ++i) v[i] = msrc[t + (i << 8)];

    float wprev_t = w_prev[(size_t)b * N_DIM + t];
    if (t < NG) pre[t] = gates[(size_t)b * GPAD + t];
    __syncthreads();

    // ---- activations ----
    if (t < 64) {
        float kt = pre[t] + bk[t];
        kvf[t] = kt;
        ev[t]  = sigmoid_f(pre[70 + t] + be[t]);
        av[t]  = pre[134 + t] + ba[t];
        float sq = warp_red_sum(kt * kt);
        if (t == 0) scal[6] = sqrtf(sq);
    }
    if (t == 64) {
        scal[0] = softplus_f(pre[64] + bbeta[0]);           // beta
        scal[1] = sigmoid_f(pre[65] + bg[0]);               // g
        float x0 = pre[66] + bs[0];
        float x1 = pre[67] + bs[1];
        float x2 = pre[68] + bs[2];
        float mxs = fmaxf(x0, fmaxf(x1, x2));
        float e0 = expf(x0 - mxs), e1 = expf(x1 - mxs), e2 = expf(x2 - mxs);
        float inv = 1.f / (e0 + e1 + e2);
        scal[3] = e0 * inv; scal[4] = e1 * inv; scal[5] = e2 * inv;
        scal[2] = 1.f + softplus_f(pre[69] + bgamma[0]);    // gamma
    }
    __syncthreads();

    // ---- partial dot/norm from registers -> padded LDS ----
    float4 kc = *(const float4*)&kvf[c << 2];
#pragma unroll
    for (int i = 0; i < 16; ++i) {
        float d, q;
        d = v[i].x * kc.x;          q = v[i].x * v[i].x;
        d = fmaf(v[i].y, kc.y, d);  q = fmaf(v[i].y, v[i].y, q);
        d = fmaf(v[i].z, kc.z, d);  q = fmaf(v[i].z, v[i].z, q);
        d = fmaf(v[i].w, kc.w, d);  q = fmaf(v[i].w, v[i].w, q);
        int n = r + (i << 4);
        pdot[n * PDS + c] = d;      // bank = (17n+c)%32: <=2-way (free)
        pnrm[n * PDS + c] = q;
    }
    __syncthreads();

    // ---- transpose-reduce: thread t = row n (stride-17 reads conflict-free) ----
    float dot = 0.f, nrm = 0.f;
#pragma unroll
    for (int j = 0; j < 16; ++j) {
        dot += pdot[t * PDS + j];
        nrm += pnrm[t * PDS + j];
    }

    float cosv = dot / (fmaxf(sqrtf(nrm), EPSC) * fmaxf(scal[6], EPSC));
    float x = scal[0] * cosv;   // beta * cos

    // ---- softmax over N=256 (one value per thread) ----
    float mx = warp_red_max(x);
    if ((t & 63) == 0) redA[t >> 6] = mx;
    __syncthreads();
    mx = fmaxf(fmaxf(redA[0], redA[1]), fmaxf(redA[2], redA[3]));
    float ex = expf(x - mx);
    float sm_ = warp_red_sum(ex);
    if ((t & 63) == 0) redB[t >> 6] = sm_;
    __syncthreads();
    float wc = ex / (redB[0] + redB[1] + redB[2] + redB[3]);

    // ---- interpolation gate ----
    float g = scal[1];
    float wg = g * wc + (1.f - g) * wprev_t;
    wgs[t] = wg;
    __syncthreads();

    // ---- circular 3-tap shift ----
    float ws_ = scal[3] * wgs[(t + 255) & 255] + scal[4] * wg + scal[5] * wgs[(t + 1) & 255];

    // ---- sharpen ----
    float wp = powf(fmaxf(ws_, 0.f), scal[2]);
    float ts = warp_red_sum(wp);
    if ((t & 63) == 0) redC[t >> 6] = ts;
    __syncthreads();
    float w = wp / (redC[0] + redC[1] + redC[2] + redC[3] + 1e-16f);

    out_w[(size_t)b * N_DIM + t] = w;
    wsh[t] = w;
    __syncthreads();

    // ---- erase/add write straight from registers, float4-coalesced ----
    float4* omem = (float4*)(out_mem + (size_t)b * (N_DIM * M_DIM));
    float4 e4 = *(const float4*)&ev[c << 2];
    float4 a4 = *(const float4*)&av[c << 2];
#pragma unroll
    for (int i = 0; i < 16; ++i) {
        float wn = wsh[r + (i << 4)];   // 16-lane broadcast, conflict-free
        float4 m_ = v[i];
        float4 rr;
        rr.x = fmaf(m_.x, -wn * e4.x, fmaf(wn, a4.x, m_.x));  // m*(1-w e) + w a
        rr.y = fmaf(m_.y, -wn * e4.y, fmaf(wn, a4.y, m_.y));
        rr.z = fmaf(m_.z, -wn * e4.z, fmaf(wn, a4.z, m_.z));
        rr.w = fmaf(m_.w, -wn * e4.w, fmaf(wn, a4.w, m_.w));
        omem[t + (i << 8)] = rr;
    }
}

extern "C" void kernel_launch(void* const* d_in, const int* in_sizes, int n_in,
                              void* d_out, int out_size, void* d_ws, size_t ws_size,
                              hipStream_t stream) {
    const float* emb    = (const float*)d_in[0];
    const float* w_prev = (const float*)d_in[1];
    const float* memory = (const float*)d_in[2];
    const float* Wk     = (const float*)d_in[3];
    const float* bk     = (const float*)d_in[4];
    const float* Wbeta  = (const float*)d_in[5];
    const float* bbeta  = (const float*)d_in[6];
    const float* Wg     = (const float*)d_in[7];
    const float* bg     = (const float*)d_in[8];
    const float* Ws     = (const float*)d_in[9];
    const float* bs     = (const float*)d_in[10];
    const float* Wgamma = (const float*)d_in[11];
    const float* bgamma = (const float*)d_in[12];
    const float* We     = (const float*)d_in[13];
    const float* be     = (const float*)d_in[14];
    const float* Wa     = (const float*)d_in[15];
    const float* ba     = (const float*)d_in[16];

    // ws layout: bf16 Wcat [GPAD,C] | bf16 embh [B,C] | fp32 gates [B,GPAD]
    const size_t WCAT_BYTES = (size_t)GPAD * C_DIM * sizeof(short);   // 416 KB
    const size_t EMBH_BYTES = (size_t)B_DIM * C_DIM * sizeof(short);  // 8 MB
    short* wcat  = (short*)d_ws;
    short* embh  = (short*)((char*)d_ws + WCAT_BYTES);
    float* gates = (float*)((char*)d_ws + WCAT_BYTES + EMBH_BYTES);

    float* out_w   = (float*)d_out;                      // [4096,256]
    float* out_mem = out_w + (size_t)B_DIM * N_DIM;      // [4096,256,64]

    build_wcat<<<(GPAD * C_DIM + 255) / 256, 256, 0, stream>>>(
        Wk, Wbeta, Wg, Ws, Wgamma, We, Wa, wcat);
    cvt_emb<<<(B_DIM * C_DIM / 8 + 255) / 256, 256, 0, stream>>>(emb, embh);
    gates_gemm<<<(B_DIM / 16) * 4, 256, 0, stream>>>(embh, wcat, gates);
    ntm_fused<<<B_DIM, 256, 0, stream>>>(w_prev, memory, gates,
                                         bk, bbeta, bg, bs, bgamma, be, ba,
                                         out_w, out_mem);
}

// Round 2
// 506.760 us; speedup vs baseline: 1.1586x; 1.0284x over previous
//
#include <hip/hip_runtime.h>
#include <hip/hip_bf16.h>

#define B_DIM 4096
#define C_DIM 1024
#define N_DIM 256
#define M_DIM 64
#define GPAD  208   // padded gate count (13 MFMA n-tiles of 16)
#define NG    198   // real gates: 64 k | 1 beta | 1 g | 3 s | 1 gamma | 64 e | 64 a
#define EPSC  1e-8f

typedef __attribute__((ext_vector_type(8))) short bfrag_t;  // 8 bf16 (4 VGPRs)
typedef __attribute__((ext_vector_type(4))) float ffrag_t;  // 4 fp32 acc
typedef __attribute__((ext_vector_type(4))) float f4;       // NT-capable float4

__device__ __forceinline__ short f2b(float f) {
    __hip_bfloat16 h = __float2bfloat16(f);
    return *reinterpret_cast<short*>(&h);
}
__device__ __forceinline__ float softplus_f(float x) {
    return fmaxf(x, 0.f) + log1pf(expf(-fabsf(x)));
}
__device__ __forceinline__ float sigmoid_f(float x) {
    return 1.f / (1.f + expf(-x));
}
__device__ __forceinline__ float warp_red_max(float v) {
#pragma unroll
    for (int off = 32; off; off >>= 1) v = fmaxf(v, __shfl_xor(v, off));
    return v;
}
__device__ __forceinline__ float warp_red_sum(float v) {
#pragma unroll
    for (int off = 32; off; off >>= 1) v += __shfl_xor(v, off);
    return v;
}
// sum across the 16-lane group (offsets 8/4/2/1 stay inside the group)
__device__ __forceinline__ float red16_sum(float v) {
#pragma unroll
    for (int off = 8; off; off >>= 1) v += __shfl_xor(v, off);
    return v;
}

// ---------------------------------------------------------------------------
// Kernel 0: prep = build_wcat + cvt_emb merged (one launch).
//  part A: pack 7 fp32 weight matrices -> bf16 Wcat[GPAD][C_DIM] (rows >=198 zero)
//  part B: convert emb fp32 -> bf16 embh (8 elems/thread, coalesced, NT reads)
// ---------------------------------------------------------------------------
#define PREP_A (GPAD * C_DIM)            // 212992 threads
#define PREP_B (B_DIM * C_DIM / 8)       // 524288 threads
__global__ __launch_bounds__(256) void prep(
    const float* __restrict__ Wk, const float* __restrict__ Wbeta,
    const float* __restrict__ Wg, const float* __restrict__ Ws,
    const float* __restrict__ Wgamma, const float* __restrict__ We,
    const float* __restrict__ Wa, const float* __restrict__ emb,
    short* __restrict__ wcat, short* __restrict__ embh)
{
    int idx = blockIdx.x * 256 + threadIdx.x;
    if (idx < PREP_A) {
        int n = idx >> 10, k = idx & (C_DIM - 1);
        float v;
        if (n < 64)        v = Wk[n * C_DIM + k];
        else if (n == 64)  v = Wbeta[k];
        else if (n == 65)  v = Wg[k];
        else if (n < 69)   v = Ws[(n - 66) * C_DIM + k];
        else if (n == 69)  v = Wgamma[k];
        else if (n < 134)  v = We[(n - 70) * C_DIM + k];
        else if (n < NG)   v = Wa[(n - 134) * C_DIM + k];
        else               v = 0.f;
        wcat[idx] = f2b(v);
        return;
    }
    int j = idx - PREP_A;
    if (j < PREP_B) {
        int base = j << 3;
        f4 a0 = __builtin_nontemporal_load((const f4*)(emb + base));
        f4 a1 = __builtin_nontemporal_load((const f4*)(emb + base + 4));
        bfrag_t f;
        f[0] = f2b(a0.x); f[1] = f2b(a0.y); f[2] = f2b(a0.z); f[3] = f2b(a0.w);
        f[4] = f2b(a1.x); f[5] = f2b(a1.y); f[6] = f2b(a1.z); f[7] = f2b(a1.w);
        *(bfrag_t*)(embh + base) = f;   // cached store: gemm re-reads from L2
    }
}

// ---------------------------------------------------------------------------
// Kernel 1: gates GEMM  pre[b, n] = emb[b,:] . Wcat[n,:]  (raw, no bias/act)
// 1024 blocks x 4 waves (4 waves/SIMD). Each wave: 16 batch rows x one
// 16-gate tile. unroll 8 -> 16 loads in flight per wave.
// ---------------------------------------------------------------------------
__global__ __launch_bounds__(256) void gates_gemm(
    const short* __restrict__ embh,
    const short* __restrict__ wcat,
    float* __restrict__ gates)
{
    const int wave = threadIdx.x >> 6;
    const int lane = threadIdx.x & 63;
    const int rg   = blockIdx.x >> 2;                  // 0..255 row-group
    const int tt   = ((blockIdx.x & 3) << 2) + wave;   // 0..15 tile
    if (tt >= 13) return;                              // padding waves exit

    const int m  = lane & 15;
    const int ko = (lane >> 4) << 3;                   // k sub-offset 0/8/16/24

    const short* arow = embh + (size_t)(rg * 16 + m) * C_DIM + ko;
    const short* brow = wcat + (size_t)(tt * 16 + m) * C_DIM + ko;

    ffrag_t acc = (ffrag_t)(0.f);
#pragma unroll 8
    for (int k = 0; k < C_DIM; k += 32) {
        bfrag_t af = *(const bfrag_t*)(arow + k);
        bfrag_t bf = *(const bfrag_t*)(brow + k);
        acc = __builtin_amdgcn_mfma_f32_16x16x32_bf16(af, bf, acc, 0, 0, 0);
    }

    // C/D layout (m89-verified): col(n) = lane&15, row(m) = (lane>>4)*4 + reg
    const int crow = rg * 16 + ((lane >> 4) << 2);
    const int n = (tt << 4) + m;
#pragma unroll
    for (int rr = 0; rr < 4; ++rr)
        gates[(size_t)(crow + rr) * GPAD + n] = acc[rr];
}

// ---------------------------------------------------------------------------
// Kernel 2: fused NTM write head. One block (256 threads) per batch row.
// v3: memory tile in registers (16 x f4/thread, NT loads). Dot/norm reduced
// IN-REGISTER via 16-lane __shfl_xor butterflies (the 16 partials of row n
// live in 16 contiguous lanes); only the 256x2 reduced values round-trip
// through a skewed 2 KB LDS transpose. LDS 38.9 KB -> ~6.4 KB.
// NT stores for out_mem (no L2 pollution from the 536 MB stream).
// ---------------------------------------------------------------------------
__global__ __launch_bounds__(256, 4) void ntm_fused(
    const float* __restrict__ w_prev,    // [B,N]
    const float* __restrict__ memory,    // [B,N,M]
    const float* __restrict__ gates,     // [B,GPAD] raw pre-activations
    const float* __restrict__ bk, const float* __restrict__ bbeta,
    const float* __restrict__ bg, const float* __restrict__ bs,
    const float* __restrict__ bgamma, const float* __restrict__ be,
    const float* __restrict__ ba,
    float* __restrict__ out_w,           // [B,N]
    float* __restrict__ out_mem)         // [B,N,M]
{
    const int b = blockIdx.x;
    const int t = threadIdx.x;
    const int r = t >> 4;     // 0..15
    const int c = t & 15;     // 0..15

    __shared__ __align__(16) float pre[NG];
    __shared__ __align__(16) float kvf[M_DIM];
    __shared__ __align__(16) float ev[M_DIM];
    __shared__ __align__(16) float av[M_DIM];
    __shared__ __align__(16) float rowdot[272];  // skewed idx n+(n>>4)
    __shared__ __align__(16) float rownrm[272];
    __shared__ float wgs[N_DIM];
    __shared__ float wsh[N_DIM];
    __shared__ float scal[8];   // 0 beta, 1 g, 2 gamma, 3..5 s, 6 k_norm
    __shared__ float redA[4], redB[4], redC[4];

    // ---- issue memory[b] loads FIRST (coalesced f4, NT, 64 VGPRs) ----
    const f4* msrc = (const f4*)(memory + (size_t)b * (N_DIM * M_DIM));
    f4 v[16];
#pragma unroll
    for (int i = 0; i < 16; ++i) v[i] = __builtin_nontemporal_load(msrc + t + (i << 8));

    float wprev_t = w_prev[(size_t)b * N_DIM + t];
    if (t < NG) pre[t] = gates[(size_t)b * GPAD + t];
    __syncthreads();

    // ---- activations (wave0: vectors, wave1 lane0: scalars, parallel) ----
    if (t < 64) {
        float kt = pre[t] + bk[t];
        kvf[t] = kt;
        ev[t]  = sigmoid_f(pre[70 + t] + be[t]);
        av[t]  = pre[134 + t] + ba[t];
        float sq = warp_red_sum(kt * kt);
        if (t == 0) scal[6] = sqrtf(sq);
    }
    if (t == 64) {
        scal[0] = softplus_f(pre[64] + bbeta[0]);           // beta
        scal[1] = sigmoid_f(pre[65] + bg[0]);               // g
        float x0 = pre[66] + bs[0];
        float x1 = pre[67] + bs[1];
        float x2 = pre[68] + bs[2];
        float mxs = fmaxf(x0, fmaxf(x1, x2));
        float e0 = expf(x0 - mxs), e1 = expf(x1 - mxs), e2 = expf(x2 - mxs);
        float inv = 1.f / (e0 + e1 + e2);
        scal[3] = e0 * inv; scal[4] = e1 * inv; scal[5] = e2 * inv;
        scal[2] = 1.f + softplus_f(pre[69] + bgamma[0]);    // gamma
    }
    __syncthreads();

    // ---- dot/norm: in-register 16-lane butterfly reduce ----
    // thread t=16r+c owns rows n=r+16i; row n's 16 partials sit in lanes 16r..16r+15
    f4 kc = ((const f4*)kvf)[c];
    float dkeep = 0.f, nkeep = 0.f;
#pragma unroll
    for (int i = 0; i < 16; ++i) {
        float d = v[i].x * kc.x,          q = v[i].x * v[i].x;
        d = fmaf(v[i].y, kc.y, d);        q = fmaf(v[i].y, v[i].y, q);
        d = fmaf(v[i].z, kc.z, d);        q = fmaf(v[i].z, v[i].z, q);
        d = fmaf(v[i].w, kc.w, d);        q = fmaf(v[i].w, v[i].w, q);
        d = red16_sum(d);                 q = red16_sum(q);
        if (c == i) { dkeep = d; nkeep = q; }   // lane c keeps row r+16c
    }
    {   // skewed store: idx n+(n>>4) = r+17c -> 16 distinct banks per group
        int nsel = r + (c << 4);
        int fi = nsel + (nsel >> 4);
        rowdot[fi] = dkeep;
        rownrm[fi] = nkeep;
    }
    __syncthreads();

    {   // transpose read: thread t takes row t (<=2-way bank alias = free)
        int ft = t + (t >> 4);
        float dot = rowdot[ft], nrm = rownrm[ft];
        float cosv = dot / (fmaxf(sqrtf(nrm), EPSC) * fmaxf(scal[6], EPSC));
        float x = scal[0] * cosv;   // beta * cos

        // ---- softmax over N=256 (one value per thread) ----
        float mx = warp_red_max(x);
        if ((t & 63) == 0) redA[t >> 6] = mx;
        __syncthreads();
        mx = fmaxf(fmaxf(redA[0], redA[1]), fmaxf(redA[2], redA[3]));
        float ex = expf(x - mx);
        float sm_ = warp_red_sum(ex);
        if ((t & 63) == 0) redB[t >> 6] = sm_;
        __syncthreads();
        float wc = ex / (redB[0] + redB[1] + redB[2] + redB[3]);

        // ---- interpolation gate ----
        float g = scal[1];
        float wg = g * wc + (1.f - g) * wprev_t;
        wgs[t] = wg;
        __syncthreads();

        // ---- circular 3-tap shift ----
        float ws_ = scal[3] * wgs[(t + 255) & 255] + scal[4] * wg
                  + scal[5] * wgs[(t + 1) & 255];

        // ---- sharpen ----
        float wp = powf(fmaxf(ws_, 0.f), scal[2]);
        float ts = warp_red_sum(wp);
        if ((t & 63) == 0) redC[t >> 6] = ts;
        __syncthreads();
        float w = wp / (redC[0] + redC[1] + redC[2] + redC[3] + 1e-16f);

        out_w[(size_t)b * N_DIM + t] = w;
        wsh[t] = w;
    }
    __syncthreads();

    // ---- erase/add write straight from registers, f4-coalesced, NT ----
    f4* omem = (f4*)(out_mem + (size_t)b * (N_DIM * M_DIM));
    f4 e4 = ((const f4*)ev)[c];
    f4 a4 = ((const f4*)av)[c];
#pragma unroll
    for (int i = 0; i < 16; ++i) {
        float wn = wsh[r + (i << 4)];   // 16-lane broadcast, conflict-free
        f4 m_ = v[i];
        f4 rr;
        rr.x = fmaf(m_.x, -wn * e4.x, fmaf(wn, a4.x, m_.x));  // m*(1-w e) + w a
        rr.y = fmaf(m_.y, -wn * e4.y, fmaf(wn, a4.y, m_.y));
        rr.z = fmaf(m_.z, -wn * e4.z, fmaf(wn, a4.z, m_.z));
        rr.w = fmaf(m_.w, -wn * e4.w, fmaf(wn, a4.w, m_.w));
        __builtin_nontemporal_store(rr, omem + t + (i << 8));
    }
}

extern "C" void kernel_launch(void* const* d_in, const int* in_sizes, int n_in,
                              void* d_out, int out_size, void* d_ws, size_t ws_size,
                              hipStream_t stream) {
    const float* emb    = (const float*)d_in[0];
    const float* w_prev = (const float*)d_in[1];
    const float* memory = (const float*)d_in[2];
    const float* Wk     = (const float*)d_in[3];
    const float* bk     = (const float*)d_in[4];
    const float* Wbeta  = (const float*)d_in[5];
    const float* bbeta  = (const float*)d_in[6];
    const float* Wg     = (const float*)d_in[7];
    const float* bg     = (const float*)d_in[8];
    const float* Ws     = (const float*)d_in[9];
    const float* bs     = (const float*)d_in[10];
    const float* Wgamma = (const float*)d_in[11];
    const float* bgamma = (const float*)d_in[12];
    const float* We     = (const float*)d_in[13];
    const float* be     = (const float*)d_in[14];
    const float* Wa     = (const float*)d_in[15];
    const float* ba     = (const float*)d_in[16];

    // ws layout: bf16 Wcat [GPAD,C] | bf16 embh [B,C] | fp32 gates [B,GPAD]
    const size_t WCAT_BYTES = (size_t)GPAD * C_DIM * sizeof(short);   // 416 KB
    const size_t EMBH_BYTES = (size_t)B_DIM * C_DIM * sizeof(short);  // 8 MB
    short* wcat  = (short*)d_ws;
    short* embh  = (short*)((char*)d_ws + WCAT_BYTES);
    float* gates = (float*)((char*)d_ws + WCAT_BYTES + EMBH_BYTES);

    float* out_w   = (float*)d_out;                      // [4096,256]
    float* out_mem = out_w + (size_t)B_DIM * N_DIM;      // [4096,256,64]

    prep<<<(PREP_A + PREP_B + 255) / 256, 256, 0, stream>>>(
        Wk, Wbeta, Wg, Ws, Wgamma, We, Wa, emb, wcat, embh);
    gates_gemm<<<(B_DIM / 16) * 4, 256, 0, stream>>>(embh, wcat, gates);
    ntm_fused<<<B_DIM, 256, 0, stream>>>(w_prev, memory, gates,
                                         bk, bbeta, bg, bs, bgamma, be, ba,
                                         out_w, out_mem);
}